// Round 5
// baseline (980.966 us; speedup 1.0000x reference)
//
#include <hip/hip_runtime.h>
#include <hip/hip_bf16.h>

typedef unsigned int u32;
typedef unsigned short u16;

// monotone float<->uint order mapping for atomicMax on floats
__device__ __forceinline__ u32 f2o(float f) {
    u32 u = __float_as_uint(f);
    return (u & 0x80000000u) ? ~u : (u | 0x80000000u);
}
__device__ __forceinline__ float o2f(u32 u) {
    return (u & 0x80000000u) ? __uint_as_float(u & 0x7fffffffu)
                             : __uint_as_float(~u);
}
__device__ __forceinline__ float lrelu(float v) {
    return v > 0.f ? v : 0.2f * v;
}

// ---------------- GEMM1: h = x @ W1  [n,128]x[128,32], + row dots ----------
__global__ __launch_bounds__(256) void gemm1_kernel(
    const float* __restrict__ x, const float* __restrict__ W,
    const float* __restrict__ a_src, const float* __restrict__ a_dst,
    float* __restrict__ h, float* __restrict__ as_, float* __restrict__ ad_,
    int n)
{
    __shared__ float xs[64][132];
    __shared__ float Wl[128][32];
    __shared__ float asv[32], adv[32];
    int t = threadIdx.x;
    int rb = blockIdx.x * 64;

    for (int i = t; i < 4096; i += 256) Wl[i >> 5][i & 31] = W[i];
    if (t < 32) { asv[t] = a_src[t]; adv[t] = a_dst[t]; }
    for (int i = t; i < 2048; i += 256) {
        int row = i >> 5, seg = i & 31;
        float4 v = make_float4(0.f, 0.f, 0.f, 0.f);
        if (rb + row < n)
            v = ((const float4*)(x + (size_t)(rb + row) * 128))[seg];
        int c = seg * 4;
        xs[row][c + 0] = v.x; xs[row][c + 1] = v.y;
        xs[row][c + 2] = v.z; xs[row][c + 3] = v.w;
    }
    __syncthreads();

    int tr = t >> 3;        // 0..31 -> rows tr, tr+32
    int tc = t & 7;         // cols tc*4 .. tc*4+3
    float acc[2][4];
#pragma unroll
    for (int i = 0; i < 2; i++)
#pragma unroll
        for (int j = 0; j < 4; j++) acc[i][j] = 0.f;

#pragma unroll 4
    for (int k = 0; k < 128; k++) {
        float x0 = xs[tr][k];
        float x1 = xs[tr + 32][k];
        float4 wv = *(const float4*)&Wl[k][tc * 4];
        acc[0][0] += x0 * wv.x; acc[0][1] += x0 * wv.y;
        acc[0][2] += x0 * wv.z; acc[0][3] += x0 * wv.w;
        acc[1][0] += x1 * wv.x; acc[1][1] += x1 * wv.y;
        acc[1][2] += x1 * wv.z; acc[1][3] += x1 * wv.w;
    }

#pragma unroll
    for (int i = 0; i < 2; i++) {
        int r = rb + tr + i * 32;
        if (r < n) {
            *(float4*)&h[(size_t)r * 32 + tc * 4] =
                make_float4(acc[i][0], acc[i][1], acc[i][2], acc[i][3]);
        }
        float ps = 0.f, pd = 0.f;
#pragma unroll
        for (int j = 0; j < 4; j++) {
            int c = tc * 4 + j;
            ps += acc[i][j] * asv[c];
            pd += acc[i][j] * adv[c];
        }
        for (int m = 1; m < 8; m <<= 1) {
            ps += __shfl_xor(ps, m, 64);
            pd += __shfl_xor(pd, m, 64);
        }
        if (tc == 0 && r < n) { as_[r] = ps; ad_[r] = pd; }
    }
}

// ---------------- layer-1 edge softmax (recompute-based, no e array) -------
__global__ __launch_bounds__(256) void l1_max_kernel(
    const int* __restrict__ srcI, const int* __restrict__ dstI,
    const float* __restrict__ as_, const float* __restrict__ ad_,
    u32* __restrict__ m1, int E, int Et)
{
    int id = blockIdx.x * 256 + threadIdx.x;
    if (id >= Et) return;
    int s, d;
    if (id < E) { s = srcI[id]; d = dstI[id]; } else { s = d = id - E; }
    float ev = lrelu(as_[s] + ad_[d]);
    atomicMax(&m1[d], f2o(ev));
}

__global__ __launch_bounds__(256) void l1_sum_kernel(
    const int* __restrict__ srcI, const int* __restrict__ dstI,
    const float* __restrict__ as_, const float* __restrict__ ad_,
    const u32* __restrict__ m1, float* __restrict__ s1, int E, int Et)
{
    int id = blockIdx.x * 256 + threadIdx.x;
    if (id >= Et) return;
    int s, d;
    if (id < E) { s = srcI[id]; d = dstI[id]; } else { s = d = id - E; }
    float ev = lrelu(as_[s] + ad_[d]);
    unsafeAtomicAdd(&s1[d], __expf(ev - o2f(m1[d])));
}

__global__ __launch_bounds__(256) void l1_agg_kernel(
    const int* __restrict__ srcI, const int* __restrict__ dstI,
    const float* __restrict__ as_, const float* __restrict__ ad_,
    const u32* __restrict__ m1, const float* __restrict__ s1,
    const float* __restrict__ h, float* __restrict__ agg, int E, int Et)
{
    int t = blockIdx.x * 256 + threadIdx.x;
    int id = t >> 5;
    int c = t & 31;
    if (id >= Et) return;
    int s, d;
    if (id < E) { s = srcI[id]; d = dstI[id]; } else { s = d = id - E; }
    float ev = lrelu(as_[s] + ad_[d]);
    float alpha = __expf(ev - o2f(m1[d])) / s1[d];
    unsafeAtomicAdd(&agg[(size_t)d * 32 + c], alpha * h[(size_t)s * 32 + c]);
}

// ---------------- GEMM2: relu(agg1+b1) @ {W_mu, W_ls} + dots ----------------
__global__ __launch_bounds__(256) void gemm2_kernel(
    const float* __restrict__ agg1, const float* __restrict__ b1,
    const float* __restrict__ Wm, const float* __restrict__ Wl_,
    const float* __restrict__ ams, const float* __restrict__ amd,
    const float* __restrict__ alsb, const float* __restrict__ ald,
    float* __restrict__ hm, float* __restrict__ hl,
    float* __restrict__ amus, float* __restrict__ amud,
    float* __restrict__ alss, float* __restrict__ alsd, int n)
{
    __shared__ float hs[16][33];
    __shared__ float Wms[32][16], Wls[32][16];
    __shared__ float amsv[16], amdv[16], alsv[16], aldv[16];
    __shared__ float b1v[32];
    int t = threadIdx.x;
    int rb = blockIdx.x * 16;

    if (t < 32) b1v[t] = b1[t];
    for (int i = t; i < 512; i += 256) {
        int k = i >> 4, c = i & 15;
        Wms[k][c] = Wm[i];
        Wls[k][c] = Wl_[i];
    }
    if (t < 16) {
        amsv[t] = ams[t]; amdv[t] = amd[t];
        alsv[t] = alsb[t]; aldv[t] = ald[t];
    }
    __syncthreads();
    for (int i = t; i < 512; i += 256) {
        int r = i >> 5, k = i & 31;
        int gr = rb + r;
        hs[r][k] = (gr < n) ? fmaxf(agg1[(size_t)gr * 32 + k] + b1v[k], 0.f) : 0.f;
    }
    __syncthreads();

    int tr = t >> 4;    // 0..15
    int c = t & 15;
    float accm = 0.f, accl = 0.f;
#pragma unroll
    for (int k = 0; k < 32; k++) {
        float hv = hs[tr][k];
        accm += hv * Wms[k][c];
        accl += hv * Wls[k][c];
    }
    int r = rb + tr;
    if (r < n) {
        hm[(size_t)r * 16 + c] = accm;
        hl[(size_t)r * 16 + c] = accl;
    }
    float pms = accm * amsv[c], pmd = accm * amdv[c];
    float pls = accl * alsv[c], pld = accl * aldv[c];
    for (int m = 1; m < 16; m <<= 1) {
        pms += __shfl_xor(pms, m, 64);
        pmd += __shfl_xor(pmd, m, 64);
        pls += __shfl_xor(pls, m, 64);
        pld += __shfl_xor(pld, m, 64);
    }
    if (c == 0 && r < n) {
        amus[r] = pms; amud[r] = pmd;
        alss[r] = pls; alsd[r] = pld;
    }
}

// ---------------- layer-2 (mu & ls combined) edge softmax -------------------
__global__ __launch_bounds__(256) void l2_max_kernel(
    const int* __restrict__ srcI, const int* __restrict__ dstI,
    const float* __restrict__ amus, const float* __restrict__ amud,
    const float* __restrict__ alss, const float* __restrict__ alsd,
    u32* __restrict__ mm, u32* __restrict__ ml, int E, int Et)
{
    int id = blockIdx.x * 256 + threadIdx.x;
    if (id >= Et) return;
    int s, d;
    if (id < E) { s = srcI[id]; d = dstI[id]; } else { s = d = id - E; }
    float evm = lrelu(amus[s] + amud[d]);
    float evl = lrelu(alss[s] + alsd[d]);
    atomicMax(&mm[d], f2o(evm));
    atomicMax(&ml[d], f2o(evl));
}

__global__ __launch_bounds__(256) void l2_sum_kernel(
    const int* __restrict__ srcI, const int* __restrict__ dstI,
    const float* __restrict__ amus, const float* __restrict__ amud,
    const float* __restrict__ alss, const float* __restrict__ alsd,
    const u32* __restrict__ mm, const u32* __restrict__ ml,
    float* __restrict__ sm, float* __restrict__ sl, int E, int Et)
{
    int id = blockIdx.x * 256 + threadIdx.x;
    if (id >= Et) return;
    int s, d;
    if (id < E) { s = srcI[id]; d = dstI[id]; } else { s = d = id - E; }
    float evm = lrelu(amus[s] + amud[d]);
    float evl = lrelu(alss[s] + alsd[d]);
    unsafeAtomicAdd(&sm[d], __expf(evm - o2f(mm[d])));
    unsafeAtomicAdd(&sl[d], __expf(evl - o2f(ml[d])));
}

__global__ __launch_bounds__(256) void l2_agg_kernel(
    const int* __restrict__ srcI, const int* __restrict__ dstI,
    const float* __restrict__ amus, const float* __restrict__ amud,
    const float* __restrict__ alss, const float* __restrict__ alsd,
    const u32* __restrict__ mm, const u32* __restrict__ ml,
    const float* __restrict__ sm, const float* __restrict__ sl,
    const float* __restrict__ hm, const float* __restrict__ hl,
    float* __restrict__ aggm, float* __restrict__ aggl, int E, int Et)
{
    int t = blockIdx.x * 256 + threadIdx.x;
    int id = t >> 4;
    int c = t & 15;
    if (id >= Et) return;
    int s, d;
    if (id < E) { s = srcI[id]; d = dstI[id]; } else { s = d = id - E; }
    float evm = lrelu(amus[s] + amud[d]);
    float evl = lrelu(alss[s] + alsd[d]);
    float am = __expf(evm - o2f(mm[d])) / sm[d];
    float al = __expf(evl - o2f(ml[d])) / sl[d];
    unsafeAtomicAdd(&aggm[(size_t)d * 16 + c], am * hm[(size_t)s * 16 + c]);
    unsafeAtomicAdd(&aggl[(size_t)d * 16 + c], al * hl[(size_t)s * 16 + c]);
}

// ---------------- output: fp32 (reference output dtype is float32) ----------
__global__ __launch_bounds__(256) void out_kernel(
    const float* __restrict__ aggm, const float* __restrict__ aggl,
    const float* __restrict__ bm, const float* __restrict__ bl,
    float* __restrict__ out, int n)
{
    int i = blockIdx.x * 256 + threadIdx.x;
    if (i >= n * 16) return;
    int c = i & 15;
    out[i] = aggm[i] + bm[c];
    out[(size_t)n * 16 + i] = aggl[i] + bl[c];
}

extern "C" void kernel_launch(void* const* d_in, const int* in_sizes, int n_in,
                              void* d_out, int out_size, void* d_ws, size_t ws_size,
                              hipStream_t stream)
{
    const float* x   = (const float*)d_in[0];
    const int*   ei  = (const int*)d_in[1];     // int32 per harness contract
    const float* W1  = (const float*)d_in[2];
    const float* a1s = (const float*)d_in[3];
    const float* a1d = (const float*)d_in[4];
    const float* b1  = (const float*)d_in[5];
    const float* Wm  = (const float*)d_in[6];
    const float* ams = (const float*)d_in[7];
    const float* amd = (const float*)d_in[8];
    const float* bm  = (const float*)d_in[9];
    const float* Wl  = (const float*)d_in[10];
    const float* als = (const float*)d_in[11];
    const float* ald = (const float*)d_in[12];
    const float* bl  = (const float*)d_in[13];

    int n  = in_sizes[0] / 128;
    int E  = in_sizes[1] / 2;
    int Et = E + n;
    const int* srcI = ei;
    const int* dstI = ei + E;

    float* ws = (float*)d_ws;
    // Compact layout, peak 72n floats = 28.8 MB:
    //  [0,32n)    h          -> reused: hm=[0,16n), hl=[16n,32n)
    //  [32n,64n)  agg1       -> reused: aggm=[32n,48n), aggl=[48n,64n)
    //  [64n..68n) m1,s1,as_,ad_ -> reused: mm,sm,ml,sl
    //  [68n,72n)  amus,amud,alss,alsd
    float* h    = ws;
    float* hm   = ws;
    float* hl   = ws + (size_t)16 * n;
    float* agg1 = ws + (size_t)32 * n;
    float* aggm = ws + (size_t)32 * n;
    float* aggl = ws + (size_t)48 * n;
    u32*   m1   = (u32*)(ws + (size_t)64 * n);
    float* s1   = ws + (size_t)65 * n;
    float* as_  = ws + (size_t)66 * n;
    float* ad_  = ws + (size_t)67 * n;
    u32*   mm   = (u32*)(ws + (size_t)64 * n);
    float* sm   = ws + (size_t)65 * n;
    u32*   ml   = (u32*)(ws + (size_t)66 * n);
    float* sl   = ws + (size_t)67 * n;
    float* amus = ws + (size_t)68 * n;
    float* amud = ws + (size_t)69 * n;
    float* alss = ws + (size_t)70 * n;
    float* alsd = ws + (size_t)71 * n;

    // zero agg1 + m1 + s1: [32n, 66n)
    hipMemsetAsync(agg1, 0, (size_t)34 * n * sizeof(float), stream);

    gemm1_kernel<<<(n + 63) / 64, 256, 0, stream>>>(x, W1, a1s, a1d, h, as_, ad_, n);

    int ge = (Et + 255) / 256;
    l1_max_kernel<<<ge, 256, 0, stream>>>(srcI, dstI, as_, ad_, m1, E, Et);
    l1_sum_kernel<<<ge, 256, 0, stream>>>(srcI, dstI, as_, ad_, m1, s1, E, Et);
    int ga1 = (int)(((long long)Et * 32 + 255) / 256);
    l1_agg_kernel<<<ga1, 256, 0, stream>>>(srcI, dstI, as_, ad_, m1, s1, h, agg1, E, Et);

    gemm2_kernel<<<(n + 15) / 16, 256, 0, stream>>>(agg1, b1, Wm, Wl, ams, amd, als, ald,
                                                    hm, hl, amus, amud, alss, alsd, n);

    // agg1/m1/s1/as_/ad_ dead; zero aggm,aggl + mm,sm,ml,sl: [32n, 68n)
    hipMemsetAsync(aggm, 0, (size_t)36 * n * sizeof(float), stream);

    l2_max_kernel<<<ge, 256, 0, stream>>>(srcI, dstI, amus, amud, alss, alsd, mm, ml, E, Et);
    l2_sum_kernel<<<ge, 256, 0, stream>>>(srcI, dstI, amus, amud, alss, alsd,
                                          mm, ml, sm, sl, E, Et);
    int ga2 = (int)(((long long)Et * 16 + 255) / 256);
    l2_agg_kernel<<<ga2, 256, 0, stream>>>(srcI, dstI, amus, amud, alss, alsd,
                                           mm, ml, sm, sl, hm, hl, aggm, aggl, E, Et);

    out_kernel<<<(n * 16 + 255) / 256, 256, 0, stream>>>(aggm, aggl, bm, bl,
                                                         (float*)d_out, n);
}

// Round 7
// 543.157 us; speedup vs baseline: 1.8060x; 1.8060x over previous
//
#include <hip/hip_runtime.h>
#include <hip/hip_bf16.h>

typedef unsigned int u32;

__device__ __forceinline__ float lrelu(float v) {
    return v > 0.f ? v : 0.2f * v;
}

// ---------------- GEMM1: h = x @ W1  [n,128]x[128,32], + row dots ----------
__global__ __launch_bounds__(256) void gemm1_kernel(
    const float* __restrict__ x, const float* __restrict__ W,
    const float* __restrict__ a_src, const float* __restrict__ a_dst,
    float* __restrict__ h, float* __restrict__ as_, float* __restrict__ ad_,
    int n)
{
    __shared__ float xs[64][132];
    __shared__ float Wl[128][32];
    __shared__ float asv[32], adv[32];
    int t = threadIdx.x;
    int rb = blockIdx.x * 64;

    for (int i = t; i < 4096; i += 256) Wl[i >> 5][i & 31] = W[i];
    if (t < 32) { asv[t] = a_src[t]; adv[t] = a_dst[t]; }
    for (int i = t; i < 2048; i += 256) {
        int row = i >> 5, seg = i & 31;
        float4 v = make_float4(0.f, 0.f, 0.f, 0.f);
        if (rb + row < n)
            v = ((const float4*)(x + (size_t)(rb + row) * 128))[seg];
        int c = seg * 4;
        xs[row][c + 0] = v.x; xs[row][c + 1] = v.y;
        xs[row][c + 2] = v.z; xs[row][c + 3] = v.w;
    }
    __syncthreads();

    int tr = t >> 3;
    int tc = t & 7;
    float acc[2][4];
#pragma unroll
    for (int i = 0; i < 2; i++)
#pragma unroll
        for (int j = 0; j < 4; j++) acc[i][j] = 0.f;

#pragma unroll 4
    for (int k = 0; k < 128; k++) {
        float x0 = xs[tr][k];
        float x1 = xs[tr + 32][k];
        float4 wv = *(const float4*)&Wl[k][tc * 4];
        acc[0][0] += x0 * wv.x; acc[0][1] += x0 * wv.y;
        acc[0][2] += x0 * wv.z; acc[0][3] += x0 * wv.w;
        acc[1][0] += x1 * wv.x; acc[1][1] += x1 * wv.y;
        acc[1][2] += x1 * wv.z; acc[1][3] += x1 * wv.w;
    }

#pragma unroll
    for (int i = 0; i < 2; i++) {
        int r = rb + tr + i * 32;
        if (r < n) {
            *(float4*)&h[(size_t)r * 32 + tc * 4] =
                make_float4(acc[i][0], acc[i][1], acc[i][2], acc[i][3]);
        }
        float ps = 0.f, pd = 0.f;
#pragma unroll
        for (int j = 0; j < 4; j++) {
            int c = tc * 4 + j;
            ps += acc[i][j] * asv[c];
            pd += acc[i][j] * adv[c];
        }
        for (int m = 1; m < 8; m <<= 1) {
            ps += __shfl_xor(ps, m, 64);
            pd += __shfl_xor(pd, m, 64);
        }
        if (tc == 0 && r < n) { as_[r] = ps; ad_[r] = pd; }
    }
}

// ---------------- CSR build ----------------
__global__ __launch_bounds__(256) void hist_kernel(
    const int* __restrict__ dstI, u32* __restrict__ deg, int E)
{
    int id = blockIdx.x * 256 + threadIdx.x;
    if (id < E) atomicAdd(&deg[dstI[id]], 1u);
}

// block sums over tiles of 2048 (deg[i]+1 to account for self-loop)
__global__ __launch_bounds__(256) void scan_bsum_kernel(
    const u32* __restrict__ deg, u32* __restrict__ bsum, int n)
{
    __shared__ u32 red[256];
    int b = blockIdx.x, t = threadIdx.x;
    int base = b * 2048;
    u32 local = 0;
    for (int i = t; i < 2048; i += 256) {
        int g = base + i;
        local += (g < n) ? deg[g] + 1u : 0u;
    }
    red[t] = local; __syncthreads();
    for (int o = 128; o > 0; o >>= 1) {
        if (t < o) red[t] += red[t + o];
        __syncthreads();
    }
    if (t == 0) bsum[b] = red[0];
}

__global__ void scan_partials_kernel(u32* bsum, int nb)
{
    if (threadIdx.x == 0) {
        u32 run = 0;
        for (int i = 0; i < nb; i++) { u32 v = bsum[i]; bsum[i] = run; run += v; }
    }
}

__global__ __launch_bounds__(256) void scan_write_kernel(
    const u32* __restrict__ deg, const u32* __restrict__ bsum,
    u32* __restrict__ rowS, int n)
{
    __shared__ u32 tsum[256];
    int b = blockIdx.x, t = threadIdx.x;
    int base = b * 2048 + t * 8;
    u32 v[8]; u32 loc = 0;
#pragma unroll
    for (int k = 0; k < 8; k++) {
        int g = base + k;
        v[k] = (g < n) ? deg[g] + 1u : 0u;
        loc += v[k];
    }
    tsum[t] = loc; __syncthreads();
    for (int o = 1; o < 256; o <<= 1) {
        u32 y = (t >= o) ? tsum[t - o] : 0u;
        __syncthreads();
        tsum[t] += y;
        __syncthreads();
    }
    u32 off = bsum[b] + tsum[t] - loc;   // exclusive
#pragma unroll
    for (int k = 0; k < 8; k++) {
        int g = base + k;
        if (g < n) rowS[g] = off;
        off += v[k];
    }
}

// cur[d] = rowS[d]; place self-loop src at last slot of segment
__global__ __launch_bounds__(256) void initcur_kernel(
    const u32* __restrict__ rowS, const u32* __restrict__ deg,
    u32* __restrict__ cur, int* __restrict__ srcS, int n)
{
    int d = blockIdx.x * 256 + threadIdx.x;
    if (d >= n) return;
    u32 r = rowS[d];
    cur[d] = r;
    srcS[r + deg[d]] = d;
}

__global__ __launch_bounds__(256) void scatter_kernel(
    const int* __restrict__ srcI, const int* __restrict__ dstI,
    u32* __restrict__ cur, int* __restrict__ srcS, int E)
{
    int id = blockIdx.x * 256 + threadIdx.x;
    if (id >= E) return;
    u32 pos = atomicAdd(&cur[dstI[id]], 1u);
    srcS[pos] = srcI[id];
}

// ---------------- layer-1 fused softmax+aggregate: one wave per dst --------
__global__ __launch_bounds__(256) void l1_fused_kernel(
    const u32* __restrict__ rowS, const u32* __restrict__ deg,
    const int* __restrict__ srcS,
    const float* __restrict__ as_, const float* __restrict__ ad_,
    const float* __restrict__ h, const float* __restrict__ b1,
    float* __restrict__ h1r, int n)
{
    int d = (blockIdx.x * 256 + threadIdx.x) >> 6;
    int lane = threadIdx.x & 63;
    if (d >= n) return;
    int beg = (int)rowS[d];
    int end = beg + (int)deg[d] + 1;
    float adv = ad_[d];
    int c = lane & 31;

    float m = -INFINITY, sum = 0.f, acc = 0.f;
    for (int base = beg; base < end; base += 64) {
        int j = base + lane;
        bool valid = j < end;
        int s = valid ? srcS[j] : 0;
        float e = valid ? lrelu(as_[s] + adv) : -INFINITY;
        float cm = e;
        for (int o = 32; o > 0; o >>= 1) cm = fmaxf(cm, __shfl_xor(cm, o, 64));
        float nm = fmaxf(m, cm);
        float scale = __expf(m - nm);         // exp(-inf)=0 on first chunk
        float p = valid ? __expf(e - nm) : 0.f;
        float ps = p;
        for (int o = 32; o > 0; o >>= 1) ps += __shfl_xor(ps, o, 64);
        sum = sum * scale + ps;
        acc *= scale;
        int cnt = end - base; if (cnt > 64) cnt = 64;
        int par = lane >> 5;                   // half 0: even edge, half 1: odd
        for (int jj = 0; jj < cnt; jj += 2) {
            int idx = jj + par;
            float pj = __shfl(p, idx, 64);
            int sj = __shfl(s, idx, 64);
            if (idx < cnt) acc += pj * h[(size_t)sj * 32 + c];
        }
        m = nm;
    }
    acc += __shfl_xor(acc, 32, 64);
    if (lane < 32)
        h1r[(size_t)d * 32 + c] = fmaxf(acc / sum + b1[c], 0.f);
}

// ---------------- GEMM2: h1r @ {W_mu, W_ls} + dots ----------------
__global__ __launch_bounds__(256) void gemm2_kernel(
    const float* __restrict__ h1r,
    const float* __restrict__ Wm, const float* __restrict__ Wl_,
    const float* __restrict__ ams, const float* __restrict__ amd,
    const float* __restrict__ alsb, const float* __restrict__ ald,
    float* __restrict__ hm, float* __restrict__ hl,
    float* __restrict__ amus, float* __restrict__ amud,
    float* __restrict__ alss, float* __restrict__ alsd, int n)
{
    __shared__ float hs[16][33];
    __shared__ float Wms[32][16], Wls[32][16];
    __shared__ float amsv[16], amdv[16], alsv[16], aldv[16];
    int t = threadIdx.x;
    int rb = blockIdx.x * 16;

    for (int i = t; i < 512; i += 256) {
        int k = i >> 4, c = i & 15;
        Wms[k][c] = Wm[i];
        Wls[k][c] = Wl_[i];
    }
    if (t < 16) {
        amsv[t] = ams[t]; amdv[t] = amd[t];
        alsv[t] = alsb[t]; aldv[t] = ald[t];
    }
    for (int i = t; i < 512; i += 256) {
        int r = i >> 5, k = i & 31;
        int gr = rb + r;
        hs[r][k] = (gr < n) ? h1r[(size_t)gr * 32 + k] : 0.f;
    }
    __syncthreads();

    int tr = t >> 4;
    int c = t & 15;
    float accm = 0.f, accl = 0.f;
#pragma unroll
    for (int k = 0; k < 32; k++) {
        float hv = hs[tr][k];
        accm += hv * Wms[k][c];
        accl += hv * Wls[k][c];
    }
    int r = rb + tr;
    if (r < n) {
        hm[(size_t)r * 16 + c] = accm;
        hl[(size_t)r * 16 + c] = accl;
    }
    float pms = accm * amsv[c], pmd = accm * amdv[c];
    float pls = accl * alsv[c], pld = accl * aldv[c];
    for (int m = 1; m < 16; m <<= 1) {
        pms += __shfl_xor(pms, m, 64);
        pmd += __shfl_xor(pmd, m, 64);
        pls += __shfl_xor(pls, m, 64);
        pld += __shfl_xor(pld, m, 64);
    }
    if (c == 0 && r < n) {
        amus[r] = pms; amud[r] = pmd;
        alss[r] = pls; alsd[r] = pld;
    }
}

// ---------------- layer-2 fused (mu & ls) + final bias -> out ---------------
__global__ __launch_bounds__(256) void l2_fused_kernel(
    const u32* __restrict__ rowS, const u32* __restrict__ deg,
    const int* __restrict__ srcS,
    const float* __restrict__ amus, const float* __restrict__ amud,
    const float* __restrict__ alss, const float* __restrict__ alsd,
    const float* __restrict__ hm, const float* __restrict__ hl,
    const float* __restrict__ bm, const float* __restrict__ bl,
    float* __restrict__ out, int n)
{
    int d = (blockIdx.x * 256 + threadIdx.x) >> 6;
    int lane = threadIdx.x & 63;
    if (d >= n) return;
    int beg = (int)rowS[d];
    int end = beg + (int)deg[d] + 1;
    float amdv = amud[d], aldv = alsd[d];
    int c = lane & 15;
    int half = lane >> 5;            // 0: mu, 1: ls
    int par = (lane >> 4) & 1;       // edge parity within half

    float m_m = -INFINITY, s_m = 0.f;
    float m_l = -INFINITY, s_l = 0.f;
    float acc = 0.f;
    const float* __restrict__ hx = half ? hl : hm;

    for (int base = beg; base < end; base += 64) {
        int j = base + lane;
        bool valid = j < end;
        int s = valid ? srcS[j] : 0;
        float em = valid ? lrelu(amus[s] + amdv) : -INFINITY;
        float el = valid ? lrelu(alss[s] + aldv) : -INFINITY;
        float cmm = em, cml = el;
        for (int o = 32; o > 0; o >>= 1) {
            cmm = fmaxf(cmm, __shfl_xor(cmm, o, 64));
            cml = fmaxf(cml, __shfl_xor(cml, o, 64));
        }
        float nmm = fmaxf(m_m, cmm), nml = fmaxf(m_l, cml);
        float scm = __expf(m_m - nmm), scl = __expf(m_l - nml);
        float pm = valid ? __expf(em - nmm) : 0.f;
        float pl = valid ? __expf(el - nml) : 0.f;
        float psm = pm, psl = pl;
        for (int o = 32; o > 0; o >>= 1) {
            psm += __shfl_xor(psm, o, 64);
            psl += __shfl_xor(psl, o, 64);
        }
        s_m = s_m * scm + psm;
        s_l = s_l * scl + psl;
        acc *= half ? scl : scm;
        int cnt = end - base; if (cnt > 64) cnt = 64;
        for (int jj = 0; jj < cnt; jj += 2) {
            int idx = jj + par;
            // CONVERGENT shuffles (all 64 lanes execute both), then select.
            // A ternary around __shfl put ds_bpermute under divergent EXEC;
            // reads from inactive source lanes return 0 -> dropped edges
            // for nodes with cnt>32 (R6 bug, absmax 0.695).
            float ajm = __shfl(pm, idx, 64);
            float ajl = __shfl(pl, idx, 64);
            int sj = __shfl(s, idx, 64);
            float aj = half ? ajl : ajm;
            if (idx < cnt) acc += aj * hx[(size_t)sj * 16 + c];
        }
        m_m = nmm; m_l = nml;
    }
    acc += __shfl_xor(acc, 16, 64);
    int q = lane >> 4;
    if (q == 0)       out[(size_t)d * 16 + c] = acc / s_m + bm[c];
    else if (q == 2)  out[(size_t)n * 16 + (size_t)d * 16 + c] = acc / s_l + bl[c];
}

extern "C" void kernel_launch(void* const* d_in, const int* in_sizes, int n_in,
                              void* d_out, int out_size, void* d_ws, size_t ws_size,
                              hipStream_t stream)
{
    const float* x   = (const float*)d_in[0];
    const int*   ei  = (const int*)d_in[1];
    const float* W1  = (const float*)d_in[2];
    const float* a1s = (const float*)d_in[3];
    const float* a1d = (const float*)d_in[4];
    const float* b1  = (const float*)d_in[5];
    const float* Wm  = (const float*)d_in[6];
    const float* ams = (const float*)d_in[7];
    const float* amd = (const float*)d_in[8];
    const float* bm  = (const float*)d_in[9];
    const float* Wl  = (const float*)d_in[10];
    const float* als = (const float*)d_in[11];
    const float* ald = (const float*)d_in[12];
    const float* bl  = (const float*)d_in[13];

    int n  = in_sizes[0] / 128;
    int E  = in_sizes[1] / 2;
    int Et = E + n;
    const int* srcI = ei;
    const int* dstI = ei + E;

    float* ws = (float*)d_ws;
    float* h    = ws;
    float* hm   = ws;
    float* hl   = ws + (size_t)16 * n;
    float* h1r  = ws + (size_t)32 * n;
    float* as_  = ws + (size_t)64 * n;
    float* ad_  = ws + (size_t)65 * n;
    float* amus = ws + (size_t)64 * n;
    float* amud = ws + (size_t)65 * n;
    float* alss = ws + (size_t)66 * n;
    float* alsd = ws + (size_t)67 * n;
    u32*   deg  = (u32*)(ws + (size_t)68 * n);
    u32*   cur  = (u32*)(ws + (size_t)69 * n);
    u32*   rowS = (u32*)(ws + (size_t)70 * n);
    int*   srcS = (int*)(ws + (size_t)71 * n);
    u32*   bsum = (u32*)(ws + (size_t)71 * n + Et);

    int nb = (n + 2047) / 2048;

    hipMemsetAsync(deg, 0, (size_t)n * sizeof(u32), stream);

    gemm1_kernel<<<(n + 63) / 64, 256, 0, stream>>>(x, W1, a1s, a1d, h, as_, ad_, n);

    hist_kernel<<<(E + 255) / 256, 256, 0, stream>>>(dstI, deg, E);
    scan_bsum_kernel<<<nb, 256, 0, stream>>>(deg, bsum, n);
    scan_partials_kernel<<<1, 64, 0, stream>>>(bsum, nb);
    scan_write_kernel<<<nb, 256, 0, stream>>>(deg, bsum, rowS, n);
    initcur_kernel<<<(n + 255) / 256, 256, 0, stream>>>(rowS, deg, cur, srcS, n);
    scatter_kernel<<<(E + 255) / 256, 256, 0, stream>>>(srcI, dstI, cur, srcS, E);

    l1_fused_kernel<<<(n + 3) / 4, 256, 0, stream>>>(rowS, deg, srcS, as_, ad_,
                                                     h, b1, h1r, n);

    gemm2_kernel<<<(n + 15) / 16, 256, 0, stream>>>(h1r, Wm, Wl, ams, amd, als, ald,
                                                    hm, hl, amus, amud, alss, alsd, n);

    l2_fused_kernel<<<(n + 3) / 4, 256, 0, stream>>>(rowS, deg, srcS,
                                                     amus, amud, alss, alsd,
                                                     hm, hl, bm, bl,
                                                     (float*)d_out, n);
}

// Round 8
// 500.566 us; speedup vs baseline: 1.9597x; 1.0851x over previous
//
#include <hip/hip_runtime.h>
#include <hip/hip_bf16.h>

typedef unsigned int u32;

__device__ __forceinline__ float lrelu(float v) {
    return v > 0.f ? v : 0.2f * v;
}

// ---------------- GEMM1: h = x @ W1  [n,128]x[128,32], + row dots ----------
__global__ __launch_bounds__(256) void gemm1_kernel(
    const float* __restrict__ x, const float* __restrict__ W,
    const float* __restrict__ a_src, const float* __restrict__ a_dst,
    float* __restrict__ h, float* __restrict__ as_, float* __restrict__ ad_,
    int n)
{
    __shared__ float xs[64][132];
    __shared__ float Wl[128][32];
    __shared__ float asv[32], adv[32];
    int t = threadIdx.x;
    int rb = blockIdx.x * 64;

    for (int i = t; i < 4096; i += 256) Wl[i >> 5][i & 31] = W[i];
    if (t < 32) { asv[t] = a_src[t]; adv[t] = a_dst[t]; }
    for (int i = t; i < 2048; i += 256) {
        int row = i >> 5, seg = i & 31;
        float4 v = make_float4(0.f, 0.f, 0.f, 0.f);
        if (rb + row < n)
            v = ((const float4*)(x + (size_t)(rb + row) * 128))[seg];
        int c = seg * 4;
        xs[row][c + 0] = v.x; xs[row][c + 1] = v.y;
        xs[row][c + 2] = v.z; xs[row][c + 3] = v.w;
    }
    __syncthreads();

    int tr = t >> 3;
    int tc = t & 7;
    float acc[2][4];
#pragma unroll
    for (int i = 0; i < 2; i++)
#pragma unroll
        for (int j = 0; j < 4; j++) acc[i][j] = 0.f;

#pragma unroll 4
    for (int k = 0; k < 128; k++) {
        float x0 = xs[tr][k];
        float x1 = xs[tr + 32][k];
        float4 wv = *(const float4*)&Wl[k][tc * 4];
        acc[0][0] += x0 * wv.x; acc[0][1] += x0 * wv.y;
        acc[0][2] += x0 * wv.z; acc[0][3] += x0 * wv.w;
        acc[1][0] += x1 * wv.x; acc[1][1] += x1 * wv.y;
        acc[1][2] += x1 * wv.z; acc[1][3] += x1 * wv.w;
    }

#pragma unroll
    for (int i = 0; i < 2; i++) {
        int r = rb + tr + i * 32;
        if (r < n) {
            *(float4*)&h[(size_t)r * 32 + tc * 4] =
                make_float4(acc[i][0], acc[i][1], acc[i][2], acc[i][3]);
        }
        float ps = 0.f, pd = 0.f;
#pragma unroll
        for (int j = 0; j < 4; j++) {
            int c = tc * 4 + j;
            ps += acc[i][j] * asv[c];
            pd += acc[i][j] * adv[c];
        }
        for (int m = 1; m < 8; m <<= 1) {
            ps += __shfl_xor(ps, m, 64);
            pd += __shfl_xor(pd, m, 64);
        }
        if (tc == 0 && r < n) { as_[r] = ps; ad_[r] = pd; }
    }
}

// ---------------- CSR build ----------------
__global__ __launch_bounds__(256) void hist_kernel(
    const int* __restrict__ dstI, u32* __restrict__ deg, int E)
{
    int id = blockIdx.x * 256 + threadIdx.x;
    if (id < E) atomicAdd(&deg[dstI[id]], 1u);
}

// block sums over tiles of 2048 (deg[i]+1 to account for self-loop)
__global__ __launch_bounds__(256) void scan_bsum_kernel(
    const u32* __restrict__ deg, u32* __restrict__ bsum, int n)
{
    __shared__ u32 red[256];
    int b = blockIdx.x, t = threadIdx.x;
    int base = b * 2048;
    u32 local = 0;
    for (int i = t; i < 2048; i += 256) {
        int g = base + i;
        local += (g < n) ? deg[g] + 1u : 0u;
    }
    red[t] = local; __syncthreads();
    for (int o = 128; o > 0; o >>= 1) {
        if (t < o) red[t] += red[t + o];
        __syncthreads();
    }
    if (t == 0) bsum[b] = red[0];
}

__global__ void scan_partials_kernel(u32* bsum, int nb)
{
    if (threadIdx.x == 0) {
        u32 run = 0;
        for (int i = 0; i < nb; i++) { u32 v = bsum[i]; bsum[i] = run; run += v; }
    }
}

// writes rowS, cur (=rowS), and the self-loop srcS slot (last slot of segment)
__global__ __launch_bounds__(256) void scan_write_kernel(
    const u32* __restrict__ deg, const u32* __restrict__ bsum,
    u32* __restrict__ rowS, u32* __restrict__ cur, int* __restrict__ srcS,
    int n)
{
    __shared__ u32 tsum[256];
    int b = blockIdx.x, t = threadIdx.x;
    int base = b * 2048 + t * 8;
    u32 v[8]; u32 loc = 0;
#pragma unroll
    for (int k = 0; k < 8; k++) {
        int g = base + k;
        v[k] = (g < n) ? deg[g] + 1u : 0u;
        loc += v[k];
    }
    tsum[t] = loc; __syncthreads();
    for (int o = 1; o < 256; o <<= 1) {
        u32 y = (t >= o) ? tsum[t - o] : 0u;
        __syncthreads();
        tsum[t] += y;
        __syncthreads();
    }
    u32 off = bsum[b] + tsum[t] - loc;   // exclusive
#pragma unroll
    for (int k = 0; k < 8; k++) {
        int g = base + k;
        if (g < n) {
            rowS[g] = off;
            cur[g]  = off;
            srcS[off + v[k] - 1u] = g;   // self-loop at last slot
        }
        off += v[k];
    }
}

// windowed scatter: group = blockIdx&15 handles dst in [grp*8192, +8192).
// All blocks of a group land on one XCD (round-robin dispatch) -> the
// group's ~557KB srcS window stays L2-resident -> write-combining works
// (R7: 104.8 MB writebacks for 6.8 MB of payload = full-line eviction
//  per 4B store due to cross-XCD thrash).
__global__ __launch_bounds__(256) void scatter_win_kernel(
    const int* __restrict__ srcI, const int* __restrict__ dstI,
    u32* __restrict__ cur, int* __restrict__ srcS, int E, int n)
{
    int grp = blockIdx.x & 15;
    int wlo = grp << 13;
    if (wlo >= n) return;
    int whi = wlo + 8192;
    int blk = blockIdx.x >> 4;
    int nblk = gridDim.x >> 4;
    int stride = nblk * 256;
    for (int i = blk * 256 + threadIdx.x; i < E; i += stride) {
        int d = dstI[i];
        if (d >= wlo && d < whi) {
            u32 pos = atomicAdd(&cur[d], 1u);
            srcS[pos] = srcI[i];
        }
    }
}

// ---------------- layer-1 fused softmax+aggregate: one wave per dst --------
__global__ __launch_bounds__(256) void l1_fused_kernel(
    const u32* __restrict__ rowS, const u32* __restrict__ deg,
    const int* __restrict__ srcS,
    const float* __restrict__ as_, const float* __restrict__ ad_,
    const float* __restrict__ h, const float* __restrict__ b1,
    float* __restrict__ h1r, int n)
{
    int d = (blockIdx.x * 256 + threadIdx.x) >> 6;
    int lane = threadIdx.x & 63;
    if (d >= n) return;
    int beg = (int)rowS[d];
    int end = beg + (int)deg[d] + 1;
    float adv = ad_[d];
    int c = lane & 31;

    float m = -INFINITY, sum = 0.f, acc = 0.f;
    for (int base = beg; base < end; base += 64) {
        int j = base + lane;
        bool valid = j < end;
        int s = valid ? srcS[j] : 0;
        float e = valid ? lrelu(as_[s] + adv) : -INFINITY;
        float cm = e;
        for (int o = 32; o > 0; o >>= 1) cm = fmaxf(cm, __shfl_xor(cm, o, 64));
        float nm = fmaxf(m, cm);
        float scale = __expf(m - nm);
        float p = valid ? __expf(e - nm) : 0.f;
        float ps = p;
        for (int o = 32; o > 0; o >>= 1) ps += __shfl_xor(ps, o, 64);
        sum = sum * scale + ps;
        acc *= scale;
        int cnt = end - base; if (cnt > 64) cnt = 64;
        int par = lane >> 5;
        for (int jj = 0; jj < cnt; jj += 2) {
            int idx = jj + par;
            float pj = __shfl(p, idx, 64);
            int sj = __shfl(s, idx, 64);
            if (idx < cnt) acc += pj * h[(size_t)sj * 32 + c];
        }
        m = nm;
    }
    acc += __shfl_xor(acc, 32, 64);
    if (lane < 32)
        h1r[(size_t)d * 32 + c] = fmaxf(acc / sum + b1[c], 0.f);
}

// ---------------- GEMM2: h1r @ {W_mu, W_ls} + dots ----------------
__global__ __launch_bounds__(256) void gemm2_kernel(
    const float* __restrict__ h1r,
    const float* __restrict__ Wm, const float* __restrict__ Wl_,
    const float* __restrict__ ams, const float* __restrict__ amd,
    const float* __restrict__ alsb, const float* __restrict__ ald,
    float* __restrict__ hm, float* __restrict__ hl,
    float* __restrict__ amus, float* __restrict__ amud,
    float* __restrict__ alss, float* __restrict__ alsd, int n)
{
    __shared__ float hs[16][33];
    __shared__ float Wms[32][16], Wls[32][16];
    __shared__ float amsv[16], amdv[16], alsv[16], aldv[16];
    int t = threadIdx.x;
    int rb = blockIdx.x * 16;

    for (int i = t; i < 512; i += 256) {
        int k = i >> 4, c = i & 15;
        Wms[k][c] = Wm[i];
        Wls[k][c] = Wl_[i];
    }
    if (t < 16) {
        amsv[t] = ams[t]; amdv[t] = amd[t];
        alsv[t] = alsb[t]; aldv[t] = ald[t];
    }
    for (int i = t; i < 512; i += 256) {
        int r = i >> 5, k = i & 31;
        int gr = rb + r;
        hs[r][k] = (gr < n) ? h1r[(size_t)gr * 32 + k] : 0.f;
    }
    __syncthreads();

    int tr = t >> 4;
    int c = t & 15;
    float accm = 0.f, accl = 0.f;
#pragma unroll
    for (int k = 0; k < 32; k++) {
        float hv = hs[tr][k];
        accm += hv * Wms[k][c];
        accl += hv * Wls[k][c];
    }
    int r = rb + tr;
    if (r < n) {
        hm[(size_t)r * 16 + c] = accm;
        hl[(size_t)r * 16 + c] = accl;
    }
    float pms = accm * amsv[c], pmd = accm * amdv[c];
    float pls = accl * alsv[c], pld = accl * aldv[c];
    for (int m = 1; m < 16; m <<= 1) {
        pms += __shfl_xor(pms, m, 64);
        pmd += __shfl_xor(pmd, m, 64);
        pls += __shfl_xor(pls, m, 64);
        pld += __shfl_xor(pld, m, 64);
    }
    if (c == 0 && r < n) {
        amus[r] = pms; amud[r] = pmd;
        alss[r] = pls; alsd[r] = pld;
    }
}

// ---------------- layer-2 fused (mu & ls) + final bias -> out ---------------
__global__ __launch_bounds__(256) void l2_fused_kernel(
    const u32* __restrict__ rowS, const u32* __restrict__ deg,
    const int* __restrict__ srcS,
    const float* __restrict__ amus, const float* __restrict__ amud,
    const float* __restrict__ alss, const float* __restrict__ alsd,
    const float* __restrict__ hm, const float* __restrict__ hl,
    const float* __restrict__ bm, const float* __restrict__ bl,
    float* __restrict__ out, int n)
{
    int d = (blockIdx.x * 256 + threadIdx.x) >> 6;
    int lane = threadIdx.x & 63;
    if (d >= n) return;
    int beg = (int)rowS[d];
    int end = beg + (int)deg[d] + 1;
    float amdv = amud[d], aldv = alsd[d];
    int c = lane & 15;
    int half = lane >> 5;
    int par = (lane >> 4) & 1;

    float m_m = -INFINITY, s_m = 0.f;
    float m_l = -INFINITY, s_l = 0.f;
    float acc = 0.f;
    const float* __restrict__ hx = half ? hl : hm;

    for (int base = beg; base < end; base += 64) {
        int j = base + lane;
        bool valid = j < end;
        int s = valid ? srcS[j] : 0;
        float em = valid ? lrelu(amus[s] + amdv) : -INFINITY;
        float el = valid ? lrelu(alss[s] + aldv) : -INFINITY;
        float cmm = em, cml = el;
        for (int o = 32; o > 0; o >>= 1) {
            cmm = fmaxf(cmm, __shfl_xor(cmm, o, 64));
            cml = fmaxf(cml, __shfl_xor(cml, o, 64));
        }
        float nmm = fmaxf(m_m, cmm), nml = fmaxf(m_l, cml);
        float scm = __expf(m_m - nmm), scl = __expf(m_l - nml);
        float pm = valid ? __expf(em - nmm) : 0.f;
        float pl = valid ? __expf(el - nml) : 0.f;
        float psm = pm, psl = pl;
        for (int o = 32; o > 0; o >>= 1) {
            psm += __shfl_xor(psm, o, 64);
            psl += __shfl_xor(psl, o, 64);
        }
        s_m = s_m * scm + psm;
        s_l = s_l * scl + psl;
        acc *= half ? scl : scm;
        int cnt = end - base; if (cnt > 64) cnt = 64;
        for (int jj = 0; jj < cnt; jj += 2) {
            int idx = jj + par;
            // CONVERGENT shuffles, then select (R6 bug: shfl under
            // divergent exec returns 0 from inactive source lanes).
            float ajm = __shfl(pm, idx, 64);
            float ajl = __shfl(pl, idx, 64);
            int sj = __shfl(s, idx, 64);
            float aj = half ? ajl : ajm;
            if (idx < cnt) acc += aj * hx[(size_t)sj * 16 + c];
        }
        m_m = nmm; m_l = nml;
    }
    acc += __shfl_xor(acc, 16, 64);
    int q = lane >> 4;
    if (q == 0)       out[(size_t)d * 16 + c] = acc / s_m + bm[c];
    else if (q == 2)  out[(size_t)n * 16 + (size_t)d * 16 + c] = acc / s_l + bl[c];
}

extern "C" void kernel_launch(void* const* d_in, const int* in_sizes, int n_in,
                              void* d_out, int out_size, void* d_ws, size_t ws_size,
                              hipStream_t stream)
{
    const float* x   = (const float*)d_in[0];
    const int*   ei  = (const int*)d_in[1];
    const float* W1  = (const float*)d_in[2];
    const float* a1s = (const float*)d_in[3];
    const float* a1d = (const float*)d_in[4];
    const float* b1  = (const float*)d_in[5];
    const float* Wm  = (const float*)d_in[6];
    const float* ams = (const float*)d_in[7];
    const float* amd = (const float*)d_in[8];
    const float* bm  = (const float*)d_in[9];
    const float* Wl  = (const float*)d_in[10];
    const float* als = (const float*)d_in[11];
    const float* ald = (const float*)d_in[12];
    const float* bl  = (const float*)d_in[13];

    int n  = in_sizes[0] / 128;
    int E  = in_sizes[1] / 2;
    int Et = E + n;
    const int* srcI = ei;
    const int* dstI = ei + E;

    float* ws = (float*)d_ws;
    float* h    = ws;
    float* hm   = ws;
    float* hl   = ws + (size_t)16 * n;
    float* h1r  = ws + (size_t)32 * n;
    float* as_  = ws + (size_t)64 * n;
    float* ad_  = ws + (size_t)65 * n;
    float* amus = ws + (size_t)64 * n;
    float* amud = ws + (size_t)65 * n;
    float* alss = ws + (size_t)66 * n;
    float* alsd = ws + (size_t)67 * n;
    u32*   deg  = (u32*)(ws + (size_t)68 * n);
    u32*   cur  = (u32*)(ws + (size_t)69 * n);
    u32*   rowS = (u32*)(ws + (size_t)70 * n);
    int*   srcS = (int*)(ws + (size_t)71 * n);
    u32*   bsum = (u32*)(ws + (size_t)71 * n + Et);

    int nb = (n + 2047) / 2048;

    hipMemsetAsync(deg, 0, (size_t)n * sizeof(u32), stream);

    gemm1_kernel<<<(n + 63) / 64, 256, 0, stream>>>(x, W1, a1s, a1d, h, as_, ad_, n);

    hist_kernel<<<(E + 255) / 256, 256, 0, stream>>>(dstI, deg, E);
    scan_bsum_kernel<<<nb, 256, 0, stream>>>(deg, bsum, n);
    scan_partials_kernel<<<1, 64, 0, stream>>>(bsum, nb);
    scan_write_kernel<<<nb, 256, 0, stream>>>(deg, bsum, rowS, cur, srcS, n);
    scatter_win_kernel<<<16 * 64, 256, 0, stream>>>(srcI, dstI, cur, srcS, E, n);

    l1_fused_kernel<<<(n + 3) / 4, 256, 0, stream>>>(rowS, deg, srcS, as_, ad_,
                                                     h, b1, h1r, n);

    gemm2_kernel<<<(n + 15) / 16, 256, 0, stream>>>(h1r, Wm, Wl, ams, amd, als, ald,
                                                    hm, hl, amus, amud, alss, alsd, n);

    l2_fused_kernel<<<(n + 3) / 4, 256, 0, stream>>>(rowS, deg, srcS,
                                                     amus, amud, alss, alsd,
                                                     hm, hl, bm, bl,
                                                     (float*)d_out, n);
}

// Round 9
// 453.484 us; speedup vs baseline: 2.1632x; 1.1038x over previous
//
#include <hip/hip_runtime.h>
#include <hip/hip_bf16.h>

typedef unsigned int u32;

__device__ __forceinline__ float lrelu(float v) {
    return v > 0.f ? v : 0.2f * v;
}

// ---------------- GEMM1: h = x @ W1  [n,128]x[128,32], + row dots ----------
__global__ __launch_bounds__(256) void gemm1_kernel(
    const float* __restrict__ x, const float* __restrict__ W,
    const float* __restrict__ a_src, const float* __restrict__ a_dst,
    float* __restrict__ h, float* __restrict__ as_, float* __restrict__ ad_,
    int n)
{
    __shared__ float xs[64][132];
    __shared__ float Wl[128][32];
    __shared__ float asv[32], adv[32];
    int t = threadIdx.x;
    int rb = blockIdx.x * 64;

    for (int i = t; i < 4096; i += 256) Wl[i >> 5][i & 31] = W[i];
    if (t < 32) { asv[t] = a_src[t]; adv[t] = a_dst[t]; }
    for (int i = t; i < 2048; i += 256) {
        int row = i >> 5, seg = i & 31;
        float4 v = make_float4(0.f, 0.f, 0.f, 0.f);
        if (rb + row < n)
            v = ((const float4*)(x + (size_t)(rb + row) * 128))[seg];
        int c = seg * 4;
        xs[row][c + 0] = v.x; xs[row][c + 1] = v.y;
        xs[row][c + 2] = v.z; xs[row][c + 3] = v.w;
    }
    __syncthreads();

    int tr = t >> 3;
    int tc = t & 7;
    float acc[2][4];
#pragma unroll
    for (int i = 0; i < 2; i++)
#pragma unroll
        for (int j = 0; j < 4; j++) acc[i][j] = 0.f;

#pragma unroll 4
    for (int k = 0; k < 128; k++) {
        float x0 = xs[tr][k];
        float x1 = xs[tr + 32][k];
        float4 wv = *(const float4*)&Wl[k][tc * 4];
        acc[0][0] += x0 * wv.x; acc[0][1] += x0 * wv.y;
        acc[0][2] += x0 * wv.z; acc[0][3] += x0 * wv.w;
        acc[1][0] += x1 * wv.x; acc[1][1] += x1 * wv.y;
        acc[1][2] += x1 * wv.z; acc[1][3] += x1 * wv.w;
    }

#pragma unroll
    for (int i = 0; i < 2; i++) {
        int r = rb + tr + i * 32;
        if (r < n) {
            *(float4*)&h[(size_t)r * 32 + tc * 4] =
                make_float4(acc[i][0], acc[i][1], acc[i][2], acc[i][3]);
        }
        float ps = 0.f, pd = 0.f;
#pragma unroll
        for (int j = 0; j < 4; j++) {
            int c = tc * 4 + j;
            ps += acc[i][j] * asv[c];
            pd += acc[i][j] * adv[c];
        }
        for (int m = 1; m < 8; m <<= 1) {
            ps += __shfl_xor(ps, m, 64);
            pd += __shfl_xor(pd, m, 64);
        }
        if (tc == 0 && r < n) { as_[r] = ps; ad_[r] = pd; }
    }
}

// ---------------- CSR build ----------------
__global__ __launch_bounds__(256) void hist_kernel(
    const int* __restrict__ dstI, u32* __restrict__ deg, int E)
{
    int id = blockIdx.x * 256 + threadIdx.x;
    if (id < E) atomicAdd(&deg[dstI[id]], 1u);
}

__global__ __launch_bounds__(256) void scan_bsum_kernel(
    const u32* __restrict__ deg, u32* __restrict__ bsum, int n)
{
    __shared__ u32 red[256];
    int b = blockIdx.x, t = threadIdx.x;
    int base = b * 2048;
    u32 local = 0;
    for (int i = t; i < 2048; i += 256) {
        int g = base + i;
        local += (g < n) ? deg[g] + 1u : 0u;
    }
    red[t] = local; __syncthreads();
    for (int o = 128; o > 0; o >>= 1) {
        if (t < o) red[t] += red[t + o];
        __syncthreads();
    }
    if (t == 0) bsum[b] = red[0];
}

__global__ void scan_partials_kernel(u32* bsum, int nb)
{
    if (threadIdx.x == 0) {
        u32 run = 0;
        for (int i = 0; i < nb; i++) { u32 v = bsum[i]; bsum[i] = run; run += v; }
    }
}

// writes rowS, cur (=rowS), and the self-loop srcS slot (last slot of segment)
__global__ __launch_bounds__(256) void scan_write_kernel(
    const u32* __restrict__ deg, const u32* __restrict__ bsum,
    u32* __restrict__ rowS, u32* __restrict__ cur, int* __restrict__ srcS,
    int n)
{
    __shared__ u32 tsum[256];
    int b = blockIdx.x, t = threadIdx.x;
    int base = b * 2048 + t * 8;
    u32 v[8]; u32 loc = 0;
#pragma unroll
    for (int k = 0; k < 8; k++) {
        int g = base + k;
        v[k] = (g < n) ? deg[g] + 1u : 0u;
        loc += v[k];
    }
    tsum[t] = loc; __syncthreads();
    for (int o = 1; o < 256; o <<= 1) {
        u32 y = (t >= o) ? tsum[t - o] : 0u;
        __syncthreads();
        tsum[t] += y;
        __syncthreads();
    }
    u32 off = bsum[b] + tsum[t] - loc;   // exclusive
#pragma unroll
    for (int k = 0; k < 8; k++) {
        int g = base + k;
        if (g < n) {
            rowS[g] = off;
            cur[g]  = off;
            srcS[off + v[k] - 1u] = g;   // self-loop at last slot
        }
        off += v[k];
    }
}

// windowed scatter: 8 windows, group = blockIdx&7 -> one XCD per window
// under round-robin dispatch; window's ~900KB srcS slice stays L2-resident
// so 4B stores write-combine (R7: cross-XCD thrash caused 65B/store).
__global__ __launch_bounds__(256) void scatter_win_kernel(
    const int* __restrict__ srcI, const int* __restrict__ dstI,
    u32* __restrict__ cur, int* __restrict__ srcS, int E, int n)
{
    int grp = blockIdx.x & 7;
    int wsz = (n + 7) >> 3;
    int wlo = grp * wsz;
    if (wlo >= n) return;
    int whi = wlo + wsz; if (whi > n) whi = n;
    int blk = blockIdx.x >> 3;
    int nblk = gridDim.x >> 3;
    int stride = nblk * 256;
    for (int i = blk * 256 + threadIdx.x; i < E; i += stride) {
        int d = dstI[i];
        if (d >= wlo && d < whi) {
            u32 pos = atomicAdd(&cur[d], 1u);
            srcS[pos] = srcI[i];
        }
    }
}

// ---------------- layer-1 fused softmax+aggregate: one wave per dst --------
__global__ __launch_bounds__(256) void l1_fused_kernel(
    const u32* __restrict__ rowS, const u32* __restrict__ deg,
    const int* __restrict__ srcS,
    const float* __restrict__ as_, const float* __restrict__ ad_,
    const float* __restrict__ h, const float* __restrict__ b1,
    float* __restrict__ h1r, int n)
{
    int d = (blockIdx.x * 256 + threadIdx.x) >> 6;
    int lane = threadIdx.x & 63;
    if (d >= n) return;
    int beg = (int)rowS[d];
    int end = beg + (int)deg[d] + 1;
    float adv = ad_[d];
    int c = lane & 31;
    int par = lane >> 5;

    float m = -INFINITY, sum = 0.f, acc = 0.f;
    for (int base = beg; base < end; base += 64) {
        int j = base + lane;
        bool valid = j < end;
        int s = valid ? srcS[j] : 0;
        float e = valid ? lrelu(as_[s] + adv) : -INFINITY;
        float cm = e;
        for (int o = 32; o > 0; o >>= 1) cm = fmaxf(cm, __shfl_xor(cm, o, 64));
        float nm = fmaxf(m, cm);
        float scale = __expf(m - nm);
        float p = valid ? __expf(e - nm) : 0.f;
        float ps = p;
        for (int o = 32; o > 0; o >>= 1) ps += __shfl_xor(ps, o, 64);
        sum = sum * scale + ps;
        acc *= scale;
        int cnt = end - base; if (cnt > 64) cnt = 64;
        // 8-edge batches: hoisted convergent shuffles, then 4 guarded
        // gathers in flight (4x MLP vs serialized 2-edge iterations).
        for (int jj = 0; jj < cnt; jj += 8) {
            float pj[4]; int sj[4];
#pragma unroll
            for (int k = 0; k < 4; k++) {
                int idx = jj + 2 * k + par;
                pj[k] = __shfl(p, idx, 64);
                sj[k] = __shfl(s, idx, 64);
            }
            float hv[4];
#pragma unroll
            for (int k = 0; k < 4; k++) {
                int idx = jj + 2 * k + par;
                hv[k] = (idx < cnt) ? h[(size_t)sj[k] * 32 + c] : 0.f;
            }
#pragma unroll
            for (int k = 0; k < 4; k++) {
                int idx = jj + 2 * k + par;
                if (idx < cnt) acc += pj[k] * hv[k];
            }
        }
        m = nm;
    }
    acc += __shfl_xor(acc, 32, 64);
    if (lane < 32)
        h1r[(size_t)d * 32 + c] = fmaxf(acc / sum + b1[c], 0.f);
}

// ---------------- GEMM2: h1r @ {W_mu, W_ls} + dots ----------------
__global__ __launch_bounds__(256) void gemm2_kernel(
    const float* __restrict__ h1r,
    const float* __restrict__ Wm, const float* __restrict__ Wl_,
    const float* __restrict__ ams, const float* __restrict__ amd,
    const float* __restrict__ alsb, const float* __restrict__ ald,
    float* __restrict__ hm, float* __restrict__ hl,
    float* __restrict__ amus, float* __restrict__ amud,
    float* __restrict__ alss, float* __restrict__ alsd, int n)
{
    __shared__ float hs[16][33];
    __shared__ float Wms[32][16], Wls[32][16];
    __shared__ float amsv[16], amdv[16], alsv[16], aldv[16];
    int t = threadIdx.x;
    int rb = blockIdx.x * 16;

    for (int i = t; i < 512; i += 256) {
        int k = i >> 4, c = i & 15;
        Wms[k][c] = Wm[i];
        Wls[k][c] = Wl_[i];
    }
    if (t < 16) {
        amsv[t] = ams[t]; amdv[t] = amd[t];
        alsv[t] = alsb[t]; aldv[t] = ald[t];
    }
    for (int i = t; i < 512; i += 256) {
        int r = i >> 5, k = i & 31;
        int gr = rb + r;
        hs[r][k] = (gr < n) ? h1r[(size_t)gr * 32 + k] : 0.f;
    }
    __syncthreads();

    int tr = t >> 4;
    int c = t & 15;
    float accm = 0.f, accl = 0.f;
#pragma unroll
    for (int k = 0; k < 32; k++) {
        float hv = hs[tr][k];
        accm += hv * Wms[k][c];
        accl += hv * Wls[k][c];
    }
    int r = rb + tr;
    if (r < n) {
        hm[(size_t)r * 16 + c] = accm;
        hl[(size_t)r * 16 + c] = accl;
    }
    float pms = accm * amsv[c], pmd = accm * amdv[c];
    float pls = accl * alsv[c], pld = accl * aldv[c];
    for (int m = 1; m < 16; m <<= 1) {
        pms += __shfl_xor(pms, m, 64);
        pmd += __shfl_xor(pmd, m, 64);
        pls += __shfl_xor(pls, m, 64);
        pld += __shfl_xor(pld, m, 64);
    }
    if (c == 0 && r < n) {
        amus[r] = pms; amud[r] = pmd;
        alss[r] = pls; alsd[r] = pld;
    }
}

// ---------------- layer-2 fused (mu & ls) + final bias -> out ---------------
__global__ __launch_bounds__(256) void l2_fused_kernel(
    const u32* __restrict__ rowS, const u32* __restrict__ deg,
    const int* __restrict__ srcS,
    const float* __restrict__ amus, const float* __restrict__ amud,
    const float* __restrict__ alss, const float* __restrict__ alsd,
    const float* __restrict__ hm, const float* __restrict__ hl,
    const float* __restrict__ bm, const float* __restrict__ bl,
    float* __restrict__ out, int n)
{
    int d = (blockIdx.x * 256 + threadIdx.x) >> 6;
    int lane = threadIdx.x & 63;
    if (d >= n) return;
    int beg = (int)rowS[d];
    int end = beg + (int)deg[d] + 1;
    float amdv = amud[d], aldv = alsd[d];
    int c = lane & 15;
    int half = lane >> 5;
    int par = (lane >> 4) & 1;

    float m_m = -INFINITY, s_m = 0.f;
    float m_l = -INFINITY, s_l = 0.f;
    float acc = 0.f;
    const float* __restrict__ hx = half ? hl : hm;

    for (int base = beg; base < end; base += 64) {
        int j = base + lane;
        bool valid = j < end;
        int s = valid ? srcS[j] : 0;
        float em = valid ? lrelu(amus[s] + amdv) : -INFINITY;
        float el = valid ? lrelu(alss[s] + aldv) : -INFINITY;
        float cmm = em, cml = el;
        for (int o = 32; o > 0; o >>= 1) {
            cmm = fmaxf(cmm, __shfl_xor(cmm, o, 64));
            cml = fmaxf(cml, __shfl_xor(cml, o, 64));
        }
        float nmm = fmaxf(m_m, cmm), nml = fmaxf(m_l, cml);
        float scm = __expf(m_m - nmm), scl = __expf(m_l - nml);
        float pm = valid ? __expf(em - nmm) : 0.f;
        float pl = valid ? __expf(el - nml) : 0.f;
        float psm = pm, psl = pl;
        for (int o = 32; o > 0; o >>= 1) {
            psm += __shfl_xor(psm, o, 64);
            psl += __shfl_xor(psl, o, 64);
        }
        s_m = s_m * scm + psm;
        s_l = s_l * scl + psl;
        acc *= half ? scl : scm;
        int cnt = end - base; if (cnt > 64) cnt = 64;
        // 8-edge batches; ALL shuffles convergent (R6 lesson), then select.
        for (int jj = 0; jj < cnt; jj += 8) {
            float pj[4]; int sj[4];
#pragma unroll
            for (int k = 0; k < 4; k++) {
                int idx = jj + 2 * k + par;
                float am = __shfl(pm, idx, 64);
                float al = __shfl(pl, idx, 64);
                sj[k] = __shfl(s, idx, 64);
                pj[k] = half ? al : am;
            }
            float hv[4];
#pragma unroll
            for (int k = 0; k < 4; k++) {
                int idx = jj + 2 * k + par;
                hv[k] = (idx < cnt) ? hx[(size_t)sj[k] * 16 + c] : 0.f;
            }
#pragma unroll
            for (int k = 0; k < 4; k++) {
                int idx = jj + 2 * k + par;
                if (idx < cnt) acc += pj[k] * hv[k];
            }
        }
        m_m = nmm; m_l = nml;
    }
    acc += __shfl_xor(acc, 16, 64);
    int q = lane >> 4;
    if (q == 0)       out[(size_t)d * 16 + c] = acc / s_m + bm[c];
    else if (q == 2)  out[(size_t)n * 16 + (size_t)d * 16 + c] = acc / s_l + bl[c];
}

extern "C" void kernel_launch(void* const* d_in, const int* in_sizes, int n_in,
                              void* d_out, int out_size, void* d_ws, size_t ws_size,
                              hipStream_t stream)
{
    const float* x   = (const float*)d_in[0];
    const int*   ei  = (const int*)d_in[1];
    const float* W1  = (const float*)d_in[2];
    const float* a1s = (const float*)d_in[3];
    const float* a1d = (const float*)d_in[4];
    const float* b1  = (const float*)d_in[5];
    const float* Wm  = (const float*)d_in[6];
    const float* ams = (const float*)d_in[7];
    const float* amd = (const float*)d_in[8];
    const float* bm  = (const float*)d_in[9];
    const float* Wl  = (const float*)d_in[10];
    const float* als = (const float*)d_in[11];
    const float* ald = (const float*)d_in[12];
    const float* bl  = (const float*)d_in[13];

    int n  = in_sizes[0] / 128;
    int E  = in_sizes[1] / 2;
    int Et = E + n;
    const int* srcI = ei;
    const int* dstI = ei + E;

    float* ws = (float*)d_ws;
    float* h    = ws;
    float* hm   = ws;
    float* hl   = ws + (size_t)16 * n;
    float* h1r  = ws + (size_t)32 * n;
    float* as_  = ws + (size_t)64 * n;
    float* ad_  = ws + (size_t)65 * n;
    float* amus = ws + (size_t)64 * n;
    float* amud = ws + (size_t)65 * n;
    float* alss = ws + (size_t)66 * n;
    float* alsd = ws + (size_t)67 * n;
    u32*   deg  = (u32*)(ws + (size_t)68 * n);
    u32*   cur  = (u32*)(ws + (size_t)69 * n);
    u32*   rowS = (u32*)(ws + (size_t)70 * n);
    int*   srcS = (int*)(ws + (size_t)71 * n);
    u32*   bsum = (u32*)(ws + (size_t)71 * n + Et);

    int nb = (n + 2047) / 2048;

    hipMemsetAsync(deg, 0, (size_t)n * sizeof(u32), stream);

    gemm1_kernel<<<(n + 63) / 64, 256, 0, stream>>>(x, W1, a1s, a1d, h, as_, ad_, n);

    hist_kernel<<<(E + 255) / 256, 256, 0, stream>>>(dstI, deg, E);
    scan_bsum_kernel<<<nb, 256, 0, stream>>>(deg, bsum, n);
    scan_partials_kernel<<<1, 64, 0, stream>>>(bsum, nb);
    scan_write_kernel<<<nb, 256, 0, stream>>>(deg, bsum, rowS, cur, srcS, n);
    scatter_win_kernel<<<8 * 64, 256, 0, stream>>>(srcI, dstI, cur, srcS, E, n);

    l1_fused_kernel<<<(n + 3) / 4, 256, 0, stream>>>(rowS, deg, srcS, as_, ad_,
                                                     h, b1, h1r, n);

    gemm2_kernel<<<(n + 15) / 16, 256, 0, stream>>>(h1r, Wm, Wl, ams, amd, als, ald,
                                                    hm, hl, amus, amud, alss, alsd, n);

    l2_fused_kernel<<<(n + 3) / 4, 256, 0, stream>>>(rowS, deg, srcS,
                                                     amus, amud, alss, alsd,
                                                     hm, hl, bm, bl,
                                                     (float*)d_out, n);
}

// Round 10
// 450.317 us; speedup vs baseline: 2.1784x; 1.0070x over previous
//
#include <hip/hip_runtime.h>
#include <hip/hip_bf16.h>

typedef unsigned int u32;
typedef unsigned long long u64;

__device__ __forceinline__ float lrelu(float v) {
    return v > 0.f ? v : 0.2f * v;
}

// ---------------- GEMM1: h = x @ W1  [n,128]x[128,32], + row dots ----------
__global__ __launch_bounds__(256) void gemm1_kernel(
    const float* __restrict__ x, const float* __restrict__ W,
    const float* __restrict__ a_src, const float* __restrict__ a_dst,
    float* __restrict__ h, float* __restrict__ as_, float* __restrict__ ad_,
    int n)
{
    __shared__ float xs[64][132];
    __shared__ float Wl[128][32];
    __shared__ float asv[32], adv[32];
    int t = threadIdx.x;
    int rb = blockIdx.x * 64;

    for (int i = t; i < 4096; i += 256) Wl[i >> 5][i & 31] = W[i];
    if (t < 32) { asv[t] = a_src[t]; adv[t] = a_dst[t]; }
    for (int i = t; i < 2048; i += 256) {
        int row = i >> 5, seg = i & 31;
        float4 v = make_float4(0.f, 0.f, 0.f, 0.f);
        if (rb + row < n)
            v = ((const float4*)(x + (size_t)(rb + row) * 128))[seg];
        int c = seg * 4;
        xs[row][c + 0] = v.x; xs[row][c + 1] = v.y;
        xs[row][c + 2] = v.z; xs[row][c + 3] = v.w;
    }
    __syncthreads();

    int tr = t >> 3;
    int tc = t & 7;
    float acc[2][4];
#pragma unroll
    for (int i = 0; i < 2; i++)
#pragma unroll
        for (int j = 0; j < 4; j++) acc[i][j] = 0.f;

#pragma unroll 4
    for (int k = 0; k < 128; k++) {
        float x0 = xs[tr][k];
        float x1 = xs[tr + 32][k];
        float4 wv = *(const float4*)&Wl[k][tc * 4];
        acc[0][0] += x0 * wv.x; acc[0][1] += x0 * wv.y;
        acc[0][2] += x0 * wv.z; acc[0][3] += x0 * wv.w;
        acc[1][0] += x1 * wv.x; acc[1][1] += x1 * wv.y;
        acc[1][2] += x1 * wv.z; acc[1][3] += x1 * wv.w;
    }

#pragma unroll
    for (int i = 0; i < 2; i++) {
        int r = rb + tr + i * 32;
        if (r < n) {
            *(float4*)&h[(size_t)r * 32 + tc * 4] =
                make_float4(acc[i][0], acc[i][1], acc[i][2], acc[i][3]);
        }
        float ps = 0.f, pd = 0.f;
#pragma unroll
        for (int j = 0; j < 4; j++) {
            int c = tc * 4 + j;
            ps += acc[i][j] * asv[c];
            pd += acc[i][j] * adv[c];
        }
        for (int m = 1; m < 8; m <<= 1) {
            ps += __shfl_xor(ps, m, 64);
            pd += __shfl_xor(pd, m, 64);
        }
        if (tc == 0 && r < n) { as_[r] = ps; ad_[r] = pd; }
    }
}

// ---------------- CSR build ----------------
__global__ __launch_bounds__(256) void hist_kernel(
    const int* __restrict__ dstI, u32* __restrict__ deg, int E)
{
    int id = blockIdx.x * 256 + threadIdx.x;
    if (id < E) atomicAdd(&deg[dstI[id]], 1u);
}

__global__ __launch_bounds__(256) void scan_bsum_kernel(
    const u32* __restrict__ deg, u32* __restrict__ bsum, int n)
{
    __shared__ u32 red[256];
    int b = blockIdx.x, t = threadIdx.x;
    int base = b * 2048;
    u32 local = 0;
    for (int i = t; i < 2048; i += 256) {
        int g = base + i;
        local += (g < n) ? deg[g] + 1u : 0u;
    }
    red[t] = local; __syncthreads();
    for (int o = 128; o > 0; o >>= 1) {
        if (t < o) red[t] += red[t + o];
        __syncthreads();
    }
    if (t == 0) bsum[b] = red[0];
}

__global__ void scan_partials_kernel(u32* bsum, int nb)
{
    if (threadIdx.x == 0) {
        u32 run = 0;
        for (int i = 0; i < nb; i++) { u32 v = bsum[i]; bsum[i] = run; run += v; }
    }
}

// writes rowS, cur (=rowS), and the self-loop srcS slot (last slot of segment)
__global__ __launch_bounds__(256) void scan_write_kernel(
    const u32* __restrict__ deg, const u32* __restrict__ bsum,
    u32* __restrict__ rowS, u32* __restrict__ cur, int* __restrict__ srcS,
    int n)
{
    __shared__ u32 tsum[256];
    int b = blockIdx.x, t = threadIdx.x;
    int base = b * 2048 + t * 8;
    u32 v[8]; u32 loc = 0;
#pragma unroll
    for (int k = 0; k < 8; k++) {
        int g = base + k;
        v[k] = (g < n) ? deg[g] + 1u : 0u;
        loc += v[k];
    }
    tsum[t] = loc; __syncthreads();
    for (int o = 1; o < 256; o <<= 1) {
        u32 y = (t >= o) ? tsum[t - o] : 0u;
        __syncthreads();
        tsum[t] += y;
        __syncthreads();
    }
    u32 off = bsum[b] + tsum[t] - loc;   // exclusive
#pragma unroll
    for (int k = 0; k < 8; k++) {
        int g = base + k;
        if (g < n) {
            rowS[g] = off;
            cur[g]  = off;
            srcS[off + v[k] - 1u] = g;   // self-loop at last slot
        }
        off += v[k];
    }
}

// per-bucket pair-array bases from rowS (bucket edge count excludes self-loops)
__global__ void bbase_kernel(const u32* __restrict__ rowS,
                             u32* __restrict__ bcur, u32* __restrict__ pbase,
                             int n, int wsz, int Et)
{
    if (threadIdx.x == 0) {
        u32 run = 0;
        for (int w = 0; w < 8; w++) {
            int lo = w * wsz; if (lo > n) lo = n;
            int hi = lo + wsz; if (hi > n) hi = n;
            u32 rlo = (lo >= n) ? (u32)Et : rowS[lo];
            u32 rhi = (hi >= n) ? (u32)Et : rowS[hi];
            u32 cw = (rhi - rlo) - (u32)(hi - lo);
            pbase[w] = run;
            bcur[w]  = run;
            run += cw;
        }
        pbase[8] = run;   // == E
    }
}

// Phase A: radix-8 partition of edges by dst window. Block-aggregated
// append: LDS rank + one global atomicAdd per bucket per chunk ->
// pair writes are sequential runs per bucket (full write-combining).
// (R9 lesson: windowed scatter over the raw edge list streams 25.6MB
//  through each XCD's L2, evicting dirty lines -> 70MB writebacks.)
#define PCHUNK 2048
__global__ __launch_bounds__(256) void partition_kernel(
    const int* __restrict__ srcI, const int* __restrict__ dstI,
    u64* __restrict__ pairs, u32* __restrict__ bcur, int E, int wsz)
{
    __shared__ u32 lcount[8];
    __shared__ u32 lbase[8];
    int t = threadIdx.x;
    for (int chunk = blockIdx.x * PCHUNK; chunk < E; chunk += gridDim.x * PCHUNK) {
        if (t < 8) lcount[t] = 0;
        __syncthreads();
        int sv[8], dv[8], wv[8]; u32 rk[8]; bool val[8];
#pragma unroll
        for (int k = 0; k < 8; k++) {
            int i = chunk + k * 256 + t;
            val[k] = i < E && (k * 256 + t) < PCHUNK;
            if (val[k]) {
                sv[k] = srcI[i];
                dv[k] = dstI[i];
                wv[k] = (u32)dv[k] / (u32)wsz;
                rk[k] = atomicAdd(&lcount[wv[k]], 1u);
            }
        }
        __syncthreads();
        if (t < 8 && lcount[t] > 0)
            lbase[t] = atomicAdd(&bcur[t], lcount[t]);
        __syncthreads();
#pragma unroll
        for (int k = 0; k < 8; k++) {
            if (val[k])
                pairs[(size_t)lbase[wv[k]] + rk[k]] =
                    ((u64)(u32)dv[k] << 32) | (u32)sv[k];
        }
        __syncthreads();
    }
}

// Phase B: each group reads ONLY its bucket (sequential ~1.7MB) and
// scatters into its ~850KB srcS window -> whole working set L2-resident.
__global__ __launch_bounds__(256) void scatter2_kernel(
    const u64* __restrict__ pairs, const u32* __restrict__ pbase,
    u32* __restrict__ cur, int* __restrict__ srcS)
{
    int grp = blockIdx.x & 7;
    int blk = blockIdx.x >> 3;
    int nblk = gridDim.x >> 3;
    u32 lo = pbase[grp], hi = pbase[grp + 1];
    u32 stride = (u32)nblk * 256u;
    for (u32 i = lo + (u32)blk * 256u + threadIdx.x; i < hi; i += stride) {
        u64 pr = pairs[i];
        int s = (int)(u32)pr;
        int d = (int)(u32)(pr >> 32);
        u32 pos = atomicAdd(&cur[d], 1u);
        srcS[pos] = s;
    }
}

// ---------------- layer-1 fused softmax+aggregate: one wave per dst --------
__global__ __launch_bounds__(256) void l1_fused_kernel(
    const u32* __restrict__ rowS, const u32* __restrict__ deg,
    const int* __restrict__ srcS,
    const float* __restrict__ as_, const float* __restrict__ ad_,
    const float* __restrict__ h, const float* __restrict__ b1,
    float* __restrict__ h1r, int n)
{
    int d = (blockIdx.x * 256 + threadIdx.x) >> 6;
    int lane = threadIdx.x & 63;
    if (d >= n) return;
    int beg = (int)rowS[d];
    int end = beg + (int)deg[d] + 1;
    float adv = ad_[d];
    int c = lane & 31;
    int par = lane >> 5;

    float m = -INFINITY, sum = 0.f, acc = 0.f;
    for (int base = beg; base < end; base += 64) {
        int j = base + lane;
        bool valid = j < end;
        int s = valid ? srcS[j] : 0;
        float e = valid ? lrelu(as_[s] + adv) : -INFINITY;
        float cm = e;
        for (int o = 32; o > 0; o >>= 1) cm = fmaxf(cm, __shfl_xor(cm, o, 64));
        float nm = fmaxf(m, cm);
        float scale = __expf(m - nm);
        float p = valid ? __expf(e - nm) : 0.f;
        float ps = p;
        for (int o = 32; o > 0; o >>= 1) ps += __shfl_xor(ps, o, 64);
        sum = sum * scale + ps;
        acc *= scale;
        int cnt = end - base; if (cnt > 64) cnt = 64;
        for (int jj = 0; jj < cnt; jj += 8) {
            float pj[4]; int sj[4];
#pragma unroll
            for (int k = 0; k < 4; k++) {
                int idx = jj + 2 * k + par;
                pj[k] = __shfl(p, idx, 64);
                sj[k] = __shfl(s, idx, 64);
            }
            float hv[4];
#pragma unroll
            for (int k = 0; k < 4; k++) {
                int idx = jj + 2 * k + par;
                hv[k] = (idx < cnt) ? h[(size_t)sj[k] * 32 + c] : 0.f;
            }
#pragma unroll
            for (int k = 0; k < 4; k++) {
                int idx = jj + 2 * k + par;
                if (idx < cnt) acc += pj[k] * hv[k];
            }
        }
        m = nm;
    }
    acc += __shfl_xor(acc, 32, 64);
    if (lane < 32)
        h1r[(size_t)d * 32 + c] = fmaxf(acc / sum + b1[c], 0.f);
}

// ---------------- GEMM2: h1r @ {W_mu, W_ls} + dots ----------------
__global__ __launch_bounds__(256) void gemm2_kernel(
    const float* __restrict__ h1r,
    const float* __restrict__ Wm, const float* __restrict__ Wl_,
    const float* __restrict__ ams, const float* __restrict__ amd,
    const float* __restrict__ alsb, const float* __restrict__ ald,
    float* __restrict__ hm, float* __restrict__ hl,
    float* __restrict__ amus, float* __restrict__ amud,
    float* __restrict__ alss, float* __restrict__ alsd, int n)
{
    __shared__ float hs[16][33];
    __shared__ float Wms[32][16], Wls[32][16];
    __shared__ float amsv[16], amdv[16], alsv[16], aldv[16];
    int t = threadIdx.x;
    int rb = blockIdx.x * 16;

    for (int i = t; i < 512; i += 256) {
        int k = i >> 4, c = i & 15;
        Wms[k][c] = Wm[i];
        Wls[k][c] = Wl_[i];
    }
    if (t < 16) {
        amsv[t] = ams[t]; amdv[t] = amd[t];
        alsv[t] = alsb[t]; aldv[t] = ald[t];
    }
    for (int i = t; i < 512; i += 256) {
        int r = i >> 5, k = i & 31;
        int gr = rb + r;
        hs[r][k] = (gr < n) ? h1r[(size_t)gr * 32 + k] : 0.f;
    }
    __syncthreads();

    int tr = t >> 4;
    int c = t & 15;
    float accm = 0.f, accl = 0.f;
#pragma unroll
    for (int k = 0; k < 32; k++) {
        float hv = hs[tr][k];
        accm += hv * Wms[k][c];
        accl += hv * Wls[k][c];
    }
    int r = rb + tr;
    if (r < n) {
        hm[(size_t)r * 16 + c] = accm;
        hl[(size_t)r * 16 + c] = accl;
    }
    float pms = accm * amsv[c], pmd = accm * amdv[c];
    float pls = accl * alsv[c], pld = accl * aldv[c];
    for (int m = 1; m < 16; m <<= 1) {
        pms += __shfl_xor(pms, m, 64);
        pmd += __shfl_xor(pmd, m, 64);
        pls += __shfl_xor(pls, m, 64);
        pld += __shfl_xor(pld, m, 64);
    }
    if (c == 0 && r < n) {
        amus[r] = pms; amud[r] = pmd;
        alss[r] = pls; alsd[r] = pld;
    }
}

// ---------------- layer-2 fused (mu & ls) + final bias -> out ---------------
__global__ __launch_bounds__(256) void l2_fused_kernel(
    const u32* __restrict__ rowS, const u32* __restrict__ deg,
    const int* __restrict__ srcS,
    const float* __restrict__ amus, const float* __restrict__ amud,
    const float* __restrict__ alss, const float* __restrict__ alsd,
    const float* __restrict__ hm, const float* __restrict__ hl,
    const float* __restrict__ bm, const float* __restrict__ bl,
    float* __restrict__ out, int n)
{
    int d = (blockIdx.x * 256 + threadIdx.x) >> 6;
    int lane = threadIdx.x & 63;
    if (d >= n) return;
    int beg = (int)rowS[d];
    int end = beg + (int)deg[d] + 1;
    float amdv = amud[d], aldv = alsd[d];
    int c = lane & 15;
    int half = lane >> 5;
    int par = (lane >> 4) & 1;

    float m_m = -INFINITY, s_m = 0.f;
    float m_l = -INFINITY, s_l = 0.f;
    float acc = 0.f;
    const float* __restrict__ hx = half ? hl : hm;

    for (int base = beg; base < end; base += 64) {
        int j = base + lane;
        bool valid = j < end;
        int s = valid ? srcS[j] : 0;
        float em = valid ? lrelu(amus[s] + amdv) : -INFINITY;
        float el = valid ? lrelu(alss[s] + aldv) : -INFINITY;
        float cmm = em, cml = el;
        for (int o = 32; o > 0; o >>= 1) {
            cmm = fmaxf(cmm, __shfl_xor(cmm, o, 64));
            cml = fmaxf(cml, __shfl_xor(cml, o, 64));
        }
        float nmm = fmaxf(m_m, cmm), nml = fmaxf(m_l, cml);
        float scm = __expf(m_m - nmm), scl = __expf(m_l - nml);
        float pm = valid ? __expf(em - nmm) : 0.f;
        float pl = valid ? __expf(el - nml) : 0.f;
        float psm = pm, psl = pl;
        for (int o = 32; o > 0; o >>= 1) {
            psm += __shfl_xor(psm, o, 64);
            psl += __shfl_xor(psl, o, 64);
        }
        s_m = s_m * scm + psm;
        s_l = s_l * scl + psl;
        acc *= half ? scl : scm;
        int cnt = end - base; if (cnt > 64) cnt = 64;
        for (int jj = 0; jj < cnt; jj += 8) {
            float pj[4]; int sj[4];
#pragma unroll
            for (int k = 0; k < 4; k++) {
                int idx = jj + 2 * k + par;
                float am = __shfl(pm, idx, 64);
                float al = __shfl(pl, idx, 64);
                sj[k] = __shfl(s, idx, 64);
                pj[k] = half ? al : am;
            }
            float hv[4];
#pragma unroll
            for (int k = 0; k < 4; k++) {
                int idx = jj + 2 * k + par;
                hv[k] = (idx < cnt) ? hx[(size_t)sj[k] * 16 + c] : 0.f;
            }
#pragma unroll
            for (int k = 0; k < 4; k++) {
                int idx = jj + 2 * k + par;
                if (idx < cnt) acc += pj[k] * hv[k];
            }
        }
        m_m = nmm; m_l = nml;
    }
    acc += __shfl_xor(acc, 16, 64);
    int q = lane >> 4;
    if (q == 0)       out[(size_t)d * 16 + c] = acc / s_m + bm[c];
    else if (q == 2)  out[(size_t)n * 16 + (size_t)d * 16 + c] = acc / s_l + bl[c];
}

extern "C" void kernel_launch(void* const* d_in, const int* in_sizes, int n_in,
                              void* d_out, int out_size, void* d_ws, size_t ws_size,
                              hipStream_t stream)
{
    const float* x   = (const float*)d_in[0];
    const int*   ei  = (const int*)d_in[1];
    const float* W1  = (const float*)d_in[2];
    const float* a1s = (const float*)d_in[3];
    const float* a1d = (const float*)d_in[4];
    const float* b1  = (const float*)d_in[5];
    const float* Wm  = (const float*)d_in[6];
    const float* ams = (const float*)d_in[7];
    const float* amd = (const float*)d_in[8];
    const float* bm  = (const float*)d_in[9];
    const float* Wl  = (const float*)d_in[10];
    const float* als = (const float*)d_in[11];
    const float* ald = (const float*)d_in[12];
    const float* bl  = (const float*)d_in[13];

    int n  = in_sizes[0] / 128;
    int E  = in_sizes[1] / 2;
    int Et = E + n;
    int wsz = (n + 7) / 8;
    const int* srcI = ei;
    const int* dstI = ei + E;

    float* ws = (float*)d_ws;
    float* h    = ws;
    float* hm   = ws;
    float* hl   = ws + (size_t)16 * n;
    float* h1r  = ws + (size_t)32 * n;
    float* as_  = ws + (size_t)64 * n;
    float* ad_  = ws + (size_t)65 * n;
    float* amus = ws + (size_t)64 * n;
    float* amud = ws + (size_t)65 * n;
    float* alss = ws + (size_t)66 * n;
    float* alsd = ws + (size_t)67 * n;
    u32*   deg  = (u32*)(ws + (size_t)68 * n);
    u32*   cur  = (u32*)(ws + (size_t)69 * n);
    u32*   rowS = (u32*)(ws + (size_t)70 * n);
    int*   srcS = (int*)(ws + (size_t)71 * n);
    u32*   bsum = (u32*)(ws + (size_t)71 * n + Et);
    u32*   bcur = bsum + 256;                   // 8
    u32*   pbase = bcur + 8;                    // 9
    // pairs: u64, aligned to 16B after the control block
    size_t pairOff = ((size_t)71 * n + Et + 300 + 3) & ~(size_t)3;
    u64*   pairs = (u64*)(ws + pairOff);

    int nb = (n + 2047) / 2048;

    hipMemsetAsync(deg, 0, (size_t)n * sizeof(u32), stream);

    gemm1_kernel<<<(n + 63) / 64, 256, 0, stream>>>(x, W1, a1s, a1d, h, as_, ad_, n);

    hist_kernel<<<(E + 255) / 256, 256, 0, stream>>>(dstI, deg, E);
    scan_bsum_kernel<<<nb, 256, 0, stream>>>(deg, bsum, n);
    scan_partials_kernel<<<1, 64, 0, stream>>>(bsum, nb);
    scan_write_kernel<<<nb, 256, 0, stream>>>(deg, bsum, rowS, cur, srcS, n);
    bbase_kernel<<<1, 64, 0, stream>>>(rowS, bcur, pbase, n, wsz, Et);
    partition_kernel<<<512, 256, 0, stream>>>(srcI, dstI, pairs, bcur, E, wsz);
    scatter2_kernel<<<8 * 128, 256, 0, stream>>>(pairs, pbase, cur, srcS);

    l1_fused_kernel<<<(n + 3) / 4, 256, 0, stream>>>(rowS, deg, srcS, as_, ad_,
                                                     h, b1, h1r, n);

    gemm2_kernel<<<(n + 15) / 16, 256, 0, stream>>>(h1r, Wm, Wl, ams, amd, als, ald,
                                                    hm, hl, amus, amud, alss, alsd, n);

    l2_fused_kernel<<<(n + 3) / 4, 256, 0, stream>>>(rowS, deg, srcS,
                                                     amus, amud, alss, alsd,
                                                     hm, hl, bm, bl,
                                                     (float*)d_out, n);
}